// Round 8
// baseline (4641.453 us; speedup 1.0000x reference)
//
#include <hip/hip_runtime.h>
#include <cmath>

typedef __attribute__((ext_vector_type(8))) short short8;
typedef __attribute__((ext_vector_type(4))) float f32x4;
typedef __attribute__((ext_vector_type(4))) unsigned int u32x4;
typedef unsigned long long u64;
typedef unsigned int u32;

#define RS 2208   // A row stride in bf16 (2176 data + 32 pad -> rows offset by 16 banks)
#define AG __ATOMIC_RELAXED, __HIP_MEMORY_SCOPE_AGENT

__device__ __forceinline__ unsigned short f2bf(float x){
  u32 u = __float_as_uint(x);
  u32 r = u + 0x7FFFu + ((u >> 16) & 1u);   // round-to-nearest-even bf16
  return (unsigned short)(r >> 16);
}

__device__ __forceinline__ float tanh_fast(float x){
  float xc = fminf(fmaxf(x, -10.f), 10.f);   // tanh(10)=1-4e-9; also keeps exp finite
  float e = __expf(2.f * xc);
  return (e - 1.f) / (e + 1.f);
}

// Pre-swizzle [w_res ; w_in] (K=2176 x 2048 cols) into bf16 MFMA B-fragment order.
// Layout: [gcg 0..127][ks 0..1][f 0..33][lane 0..63][j 0..7]:
//   k = ks*1088 + f*32 + (l>>4)*8 + j, col = gcg*16 + (l&15).
__global__ void bswz_kernel(const float* __restrict__ wres,
                            const float* __restrict__ win,
                            unsigned short* __restrict__ B){
  int tid = blockIdx.x * 256 + threadIdx.x;
  int l   = tid & 63;
  int cf  = tid >> 6;          // (gcg*2+ks)*34 + f
  int f   = cf % 34;
  int gk  = cf / 34;
  int ks  = gk & 1;
  int gcg = gk >> 1;
  int col = (gcg << 4) + (l & 15);
  int k0  = ks * 1088 + (f << 5) + ((l >> 4) << 3);
  short8 vv;
  #pragma unroll
  for (int j = 0; j < 8; ++j){
    int k = k0 + j;
    float v = (k < 2048) ? wres[(size_t)k * 2048 + col]
                         : win[(size_t)(k - 2048) * 2048 + col];
    vv[j] = (short)f2bf(v);
  }
  *((short8*)(B + (size_t)tid * 8)) = vv;
}

// out[b][t][0:128] = inputs  (concat head).  262144 float4s = 1024 blocks x 256.
__global__ void copy_in_kernel(const float* __restrict__ in, float* __restrict__ out){
  int i = blockIdx.x * 256 + threadIdx.x;
  int bt = i >> 5;
  int d4 = i & 31;
  float4 v = ((const float4*)in)[i];
  ((float4*)(out + (size_t)bt * 2176))[d4] = v;
}

// Exchange init: ex[2][8][512] u64.  Parity 0 = 0 (tag-bit 0, s_0 = 0 -> valid for t=0).
// Parity 1 = all-bf16-LSB=1 (tag-bit 1): t=1 wants bit 0 -> init rejected until real data.
__global__ void exinit_kernel(u64* __restrict__ ex){
  int i = blockIdx.x * 256 + threadIdx.x;   // 8192 entries
  ex[i] = (i < 4096) ? 0ULL : 0x0001000100010001ULL;
}

// Persistent ESN scan: 128 blocks x 512 threads = 4 row-pairs x 32 col-blocks of 64 cols.
// Exchange entries: u64 = 4 consecutive columns' bf16 with LSB = step tag-bit ((t>>1)&1).
// Double-buffered by parity; stale slot is always step t-2 whose tag-bit differs.
// r8 transport fix: fast-path polls are NON-TEMPORAL (sc0 sc1 nt) -- no L2 allocation,
// so there is no cached copy to invalidate and no per-step miss+refill round-trip
// (r6/r7 FETCH data showed each polled line refetched once per XCD per step = the
// coherence cycle was the step cost). Every 8th iteration falls back to the proven
// __hip_atomic_load pair, so liveness/correctness never depend on nt semantics.
__global__ void __launch_bounds__(512, 2) esn_persist(
    const float* __restrict__ inputs,
    const float* __restrict__ b_in,
    const unsigned short* __restrict__ Bsw,
    u64* __restrict__ ex,          // ex[parity 2][row 8][512 entries]
    float* __restrict__ out)
{
  __shared__ __align__(16) unsigned short As[2 * RS];  // [row 0/1][k: 2048 state + 128 x_t + pad]
  __shared__ float red[2][4][16][2];                   // [parity][cg][m16][row]

  const int tid = threadIdx.x;
  const int blk = blockIdx.x;      // 0..127
  const int r0  = (blk >> 5) << 1; // batch rows {r0, r0+1}
  const int cb  = blk & 31;        // column block: cols [cb*64, cb*64+64)
  const int wv  = tid >> 6;        // 0..7
  const int l   = tid & 63;
  const int m16 = l & 15;
  const int q   = l >> 4;
  const int cg  = wv >> 1;         // col-group 0..3 (16 cols each)
  const int ks  = wv & 1;          // K-split 0/1 (K=1088 each)
  const int gcg = (cb << 2) + cg;  // global col-group 0..127
  const int colw0 = gcg << 4;

  // B fragments in registers for the whole scan (34 per wave = 136 VGPRs)
  short8 Bf[34];
  {
    const short8* bp = (const short8*)Bsw + (size_t)((gcg << 1) + ks) * 34 * 64 + l;
    #pragma unroll
    for (int f = 0; f < 34; ++f) Bf[f] = bp[f * 64];
  }
  const float bias = b_in[colw0 + m16];
  float s0 = 0.f, s1 = 0.f;        // fp32 leak-path state (ks==0, lanes<16)

  const float* xr0 = inputs + (size_t)r0 * 1024 * 128;
  const u64 M = 0x0001000100010001ULL;

  // register x-prefetch (r6-proven): overlaps the global x load with the poll
  float4 xv;
  if (tid < 64) xv = ((const float4*)(xr0 + (size_t)(tid >> 5) * 1024 * 128))[tid & 31];

  for (int t = 0; t < 1024; ++t){
    // ---- stage x_t from regs: 64 threads, packed 8B LDS writes; prefetch x_{t+1} ----
    if (tid < 64){
      const int row = tid >> 5;
      const int c   = tid & 31;
      u64 pk = (u64)f2bf(xv.x) | ((u64)f2bf(xv.y) << 16)
             | ((u64)f2bf(xv.z) << 32) | ((u64)f2bf(xv.w) << 48);
      *((u64*)&As[row * RS + 2048 + (c << 2)]) = pk;
      if (t < 1023)
        xv = ((const float4*)(xr0 + ((size_t)row * 1024 + t + 1) * 128))[c];
    }
    // ---- poll: one 16B load/thread covering its 2 adjacent entries ----
    // rows r0, r0+1 are contiguous in ex => entries [0,1024) span both rows.
    {
      u64* srcb = ex + ((size_t)(t & 1) * 8 + r0) * 512;   // 1024 u64 across 2 rows
      const u64 want = ((t >> 1) & 1) ? M : 0ULL;
      const u64* myp = &srcb[tid << 1];
      u64 v0, v1;
      u32 it = 0;
      for (;;){
        if ((it & 7u) == 7u){           // proven-path fallback: liveness guaranteed
          v0 = __hip_atomic_load(&myp[0], AG);
          v1 = __hip_atomic_load(&myp[1], AG);
        } else {
          u32x4 v;
          asm volatile("global_load_dwordx4 %0, %1, off sc0 sc1 nt\n\ts_waitcnt vmcnt(0)"
                       : "=v"(v) : "v"(myp) : "memory");
          v0 = (u64)v.x | ((u64)v.y << 32);
          v1 = (u64)v.z | ((u64)v.w << 32);
        }
        if (((v0 & M) == want) && ((v1 & M) == want)) break;
        ++it;
      }
      const int row = tid >> 8;          // 0/1
      const int e   = tid & 255;         // 16B pair index within the row
      u64* dst = (u64*)&As[row * RS + (e << 3)];   // e*16 bytes, 16B-aligned
      dst[0] = v0; dst[1] = v1;
    }
    __syncthreads();

    // ---- MFMA: M=2, K=1088 per wave, 34 x 16x16x32, 2 interleaved acc chains.
    // Unconditional A read, row = m16&1: 8 lanes/address -> free LDS broadcast;
    // lanes m16>=2 feed garbage into D rows 2..15 which are never read.
    f32x4 acc0 = {0.f,0.f,0.f,0.f}, acc1 = {0.f,0.f,0.f,0.f};
    {
      const unsigned short* Ab = &As[(m16 & 1) * RS + ks * 1088 + (q << 3)];
      #pragma unroll
      for (int f = 0; f < 34; f += 2){
        short8 a0 = *((const short8*)(Ab + (f << 5)));
        short8 a1 = *((const short8*)(Ab + ((f + 1) << 5)));
        acc0 = __builtin_amdgcn_mfma_f32_16x16x32_bf16(a0, Bf[f],     acc0, 0, 0, 0);
        acc1 = __builtin_amdgcn_mfma_f32_16x16x32_bf16(a1, Bf[f + 1], acc1, 0, 0, 0);
      }
    }
    // C/D: col=l&15, row=q*4+reg -> batch rows 0,1 live in lanes 0..15, regs 0,1
    float p0 = acc0[0] + acc1[0];
    float p1 = acc0[1] + acc1[1];
    if (ks == 1 && l < 16){
      red[t & 1][cg][m16][0] = p0;
      red[t & 1][cg][m16][1] = p1;
    }
    __syncthreads();

    // ---- ks==0 lanes<16: reduce, tanh, leak, publish FIRST, then out stores ----
    if (ks == 0 && l < 16){
      p0 += red[t & 1][cg][m16][0];
      p1 += red[t & 1][cg][m16][1];
      float nv0 = 0.5f * s0 + 0.5f * tanh_fast(p0 + bias);
      float nv1 = 0.5f * s1 + 0.5f * tanh_fast(p1 + bias);
      s0 = nv0; s1 = nv1;
      const u32 bit = (u32)(((t + 1) >> 1) & 1);
      u32 b0 = ((u32)f2bf(nv0) & 0xFFFEu) | bit;   // tag-bit in bf16 LSB
      u32 b1 = ((u32)f2bf(nv1) & 0xFFFEu) | bit;
      // pack 4 lanes' cols into one u64 (valid on lanes m16%4==0)
      u32 pr0 = b0 | (((u32)__shfl_xor((int)b0, 1)) << 16);
      u32 pr1 = b1 | (((u32)__shfl_xor((int)b1, 1)) << 16);
      u64 e0 = (u64)pr0 | ((u64)(u32)__shfl_xor((int)pr0, 2) << 32);
      u64 e1 = (u64)pr1 | ((u64)(u32)__shfl_xor((int)pr1, 2) << 32);
      const int u = colw0 + m16;
      if ((m16 & 3) == 0){
        u64* exw = ex + ((size_t)((t + 1) & 1) * 8 + r0) * 512;
        const int p = (colw0 + m16) >> 2;
        // publish via RMW at the coherence point (r7; >= store path, keeps MALL visibility)
        (void)__hip_atomic_exchange(&exw[p],       e0, AG);
        (void)__hip_atomic_exchange(&exw[512 + p], e1, AG);
      }
      float pw0 = (u & 1) ? nv0 : nv0 * nv0;       // PowerIndex: even u squared
      float pw1 = (u & 1) ? nv1 : nv1 * nv1;
      out[((size_t)r0 * 1024 + t) * 2176 + 128 + u] = pw0;
      out[((size_t)(r0 + 1) * 1024 + t) * 2176 + 128 + u] = pw1;
    }
    // no third barrier: As reads complete before barrier 2; red is parity-double-buffered
  }
}

extern "C" void kernel_launch(void* const* d_in, const int* in_sizes, int n_in,
                              void* d_out, int out_size, void* d_ws, size_t ws_size,
                              hipStream_t stream){
  const float* inputs = (const float*)d_in[0];   // [8,1024,128]
  const float* w_in   = (const float*)d_in[1];   // [128,2048]
  const float* b_in   = (const float*)d_in[2];   // [2048]
  const float* w_res  = (const float*)d_in[3];   // [2048,2048]
  float* out = (float*)d_out;

  u64* ex = (u64*)d_ws;                                         // 2*8*512*8 = 65536 B
  unsigned short* Bsw = (unsigned short*)((char*)d_ws + 65536); // 8,912,896 B swizzled weights

  exinit_kernel<<<32, 256, 0, stream>>>(ex);
  bswz_kernel<<<2176, 256, 0, stream>>>(w_res, w_in, Bsw);
  copy_in_kernel<<<1024, 256, 0, stream>>>(inputs, out);
  esn_persist<<<128, 512, 0, stream>>>(inputs, b_in, Bsw, ex, out);
}